// Round 1
// baseline (1928.000 us; speedup 1.0000x reference)
//
#include <hip/hip_runtime.h>
#include <cstddef>

// Problem constants
constexpr int nB = 8;
constexpr int nC = 256;
constexpr int nN = 768;
constexpr int nT = 12;
constexpr int nM = nN * nT;      // 9216
constexpr int nH = 64;           // hidden
constexpr float SCALE = 0.125f;  // 64^-0.5
constexpr float LNEPS = 1e-6f;

// ---------------------------------------------------------------------------
// LayerNorm over channel axis (axis 1) of [B, C, N, T].
// Block: 256 threads = 64 m-positions x 4 channel-groups. Two passes; second
// pass is L2-hot (block footprint 64 KB).
// ---------------------------------------------------------------------------
__global__ __launch_bounds__(256) void ln_cf(const float* __restrict__ X,
                                             const float* __restrict__ w,
                                             const float* __restrict__ bias,
                                             float* __restrict__ Y)
{
    int lane = threadIdx.x & 63;
    int cg = threadIdx.x >> 6;
    int m = blockIdx.x * 64 + lane;
    int b = blockIdx.y;
    size_t base = (size_t)b * nC * nM + m;
    float s = 0.f, ss = 0.f;
#pragma unroll 4
    for (int k = 0; k < 64; ++k) {
        float v = X[base + (size_t)(cg * 64 + k) * nM];
        s += v; ss += v * v;
    }
    __shared__ float rs[4][64], rss[4][64], mu_s[64], rstd_s[64];
    rs[cg][lane] = s; rss[cg][lane] = ss;
    __syncthreads();
    if (threadIdx.x < 64) {
        float t1 = rs[0][lane] + rs[1][lane] + rs[2][lane] + rs[3][lane];
        float t2 = rss[0][lane] + rss[1][lane] + rss[2][lane] + rss[3][lane];
        float mu = t1 * (1.f / nC);
        float var = t2 * (1.f / nC) - mu * mu;
        mu_s[lane] = mu;
        rstd_s[lane] = rsqrtf(var + LNEPS);
    }
    __syncthreads();
    float mu = mu_s[lane], rstd = rstd_s[lane];
#pragma unroll 4
    for (int k = 0; k < 64; ++k) {
        int c = cg * 64 + k;
        float v = X[base + (size_t)c * nM];
        Y[base + (size_t)c * nM] = (v - mu) * rstd * w[c] + bias[c];
    }
}

// ---------------------------------------------------------------------------
// Channels-last projection: OUT[b, m', h] = sum_c X[b,c,m] * W(c,h) + bias[h]
// X: [B, 256, 9216] channels-first (LN output). H = 64.
// PERM: output row index is (b, t, n) (m = n*T + t) instead of (b, m).
// WTRANS: W stored [h][c] (v_w) instead of [c][h] (Wnq etc).
// Tile: 64 m x 64 h, K-chunk 32. Block 256, 4x4 microtile.
// ---------------------------------------------------------------------------
template <bool PERM, bool WTRANS>
__global__ __launch_bounds__(256) void convgemm_cl(const float* __restrict__ X,
                                                   const float* __restrict__ W,
                                                   const float* __restrict__ bias,
                                                   float* __restrict__ OUT)
{
    __shared__ __align__(16) float Xs[32][68];
    __shared__ __align__(16) float Ws[32][68];
    int tid = threadIdx.x;
    int m0 = blockIdx.x * 64;
    int b = blockIdx.y;
    const float* Xb = X + (size_t)b * nC * nM;
    float acc[4][4] = {};
    int mbase = (tid >> 4) * 4;
    int hbase = (tid & 15) * 4;
    for (int k0 = 0; k0 < nC; k0 += 32) {
        {   // stage X tile (coalesced along m)
            int m = tid & 63, kk = tid >> 6;
#pragma unroll
            for (int r = 0; r < 8; ++r) {
                int k = kk + r * 4;
                Xs[k][m] = Xb[(size_t)(k0 + k) * nM + m0 + m];
            }
        }
        if (!WTRANS) {  // W[c][h], h contiguous
            int h = tid & 63, kk = tid >> 6;
#pragma unroll
            for (int r = 0; r < 8; ++r) {
                int k = kk + r * 4;
                Ws[k][h] = W[(size_t)(k0 + k) * 64 + h];
            }
        } else {        // W[h][c], c contiguous
            int k = tid & 31, hh = tid >> 5;
#pragma unroll
            for (int r = 0; r < 8; ++r) {
                int h = hh + r * 8;
                Ws[k][h] = W[(size_t)h * nC + k0 + k];
            }
        }
        __syncthreads();
#pragma unroll
        for (int k = 0; k < 32; ++k) {
            float4 av = *(const float4*)&Xs[k][mbase];
            float4 bv = *(const float4*)&Ws[k][hbase];
            float a[4] = {av.x, av.y, av.z, av.w};
            float c[4] = {bv.x, bv.y, bv.z, bv.w};
#pragma unroll
            for (int i = 0; i < 4; ++i)
#pragma unroll
                for (int j = 0; j < 4; ++j) acc[i][j] += a[i] * c[j];
        }
        __syncthreads();
    }
    float4 bv = *(const float4*)&bias[hbase];
    float bb[4] = {bv.x, bv.y, bv.z, bv.w};
#pragma unroll
    for (int i = 0; i < 4; ++i) {
        int m = m0 + mbase + i;
        size_t row;
        if (PERM) { int n = m / nT, t = m % nT; row = ((size_t)b * nT + t) * nN + n; }
        else      { row = (size_t)b * nM + m; }
        float4 o;
        o.x = acc[i][0] + bb[0]; o.y = acc[i][1] + bb[1];
        o.z = acc[i][2] + bb[2]; o.w = acc[i][3] + bb[3];
        *(float4*)&OUT[row * 64 + hbase] = o;
    }
}

// ---------------------------------------------------------------------------
// Node attention raw scores: S[bt, i, j] = SCALE * <nq_i, nk_j> + Bn[i,j]
// nq/nk: [B*T, 768, 64] h-contiguous. Tile 64x64, K=64 (single chunk).
// ---------------------------------------------------------------------------
__global__ __launch_bounds__(256) void node_scores(const float* __restrict__ NQ,
                                                   const float* __restrict__ NK,
                                                   const float* __restrict__ Bn,
                                                   float* __restrict__ S)
{
    __shared__ __align__(16) float Qs[64][68];  // [h][i]
    __shared__ __align__(16) float Ks[64][68];  // [h][j]
    int tid = threadIdx.x;
    int j0 = blockIdx.x * 64, i0 = blockIdx.y * 64, bt = blockIdx.z;
    const float* NQb = NQ + (size_t)bt * nN * 64;
    const float* NKb = NK + (size_t)bt * nN * 64;
    {
        int h = tid & 63, rr = tid >> 6;
#pragma unroll
        for (int r = 0; r < 16; ++r) {
            int i = rr + r * 4;
            Qs[h][i] = NQb[(size_t)(i0 + i) * 64 + h];
            Ks[h][i] = NKb[(size_t)(j0 + i) * 64 + h];
        }
    }
    __syncthreads();
    int ibase = (tid >> 4) * 4, jbase = (tid & 15) * 4;
    float acc[4][4] = {};
#pragma unroll
    for (int h = 0; h < 64; ++h) {
        float4 av = *(const float4*)&Qs[h][ibase];
        float4 bv = *(const float4*)&Ks[h][jbase];
        float a[4] = {av.x, av.y, av.z, av.w};
        float c[4] = {bv.x, bv.y, bv.z, bv.w};
#pragma unroll
        for (int i = 0; i < 4; ++i)
#pragma unroll
            for (int j = 0; j < 4; ++j) acc[i][j] += a[i] * c[j];
    }
#pragma unroll
    for (int i = 0; i < 4; ++i) {
        int irow = i0 + ibase + i;
        float4 bn = *(const float4*)&Bn[(size_t)irow * nN + j0 + jbase];
        float4 o;
        o.x = acc[i][0] * SCALE + bn.x;
        o.y = acc[i][1] * SCALE + bn.y;
        o.z = acc[i][2] * SCALE + bn.z;
        o.w = acc[i][3] * SCALE + bn.w;
        *(float4*)&S[((size_t)bt * nN + irow) * nN + j0 + jbase] = o;
    }
}

// ---------------------------------------------------------------------------
// Row softmax (over j) then elementwise * adj. In-place on S.
// One wave per row; 4 rows per 256-thread block. Row = 768 = 3 float4/lane.
// ---------------------------------------------------------------------------
__global__ __launch_bounds__(256) void softmax_adj(float* __restrict__ S,
                                                   const float* __restrict__ adj)
{
    int bt = blockIdx.y;
    int i = blockIdx.x * 4 + (threadIdx.x >> 6);
    int lane = threadIdx.x & 63;
    size_t row = ((size_t)bt * nN + i) * nN;
    const float4* p = (const float4*)(S + row);
    float4 v[3];
    float m = -1e30f;
#pragma unroll
    for (int r = 0; r < 3; ++r) {
        v[r] = p[lane + r * 64];
        m = fmaxf(m, fmaxf(fmaxf(v[r].x, v[r].y), fmaxf(v[r].z, v[r].w)));
    }
#pragma unroll
    for (int off = 32; off; off >>= 1) m = fmaxf(m, __shfl_xor(m, off));
    float sum = 0.f;
#pragma unroll
    for (int r = 0; r < 3; ++r) {
        v[r].x = expf(v[r].x - m); v[r].y = expf(v[r].y - m);
        v[r].z = expf(v[r].z - m); v[r].w = expf(v[r].w - m);
        sum += v[r].x + v[r].y + v[r].z + v[r].w;
    }
#pragma unroll
    for (int off = 32; off; off >>= 1) sum += __shfl_xor(sum, off);
    float inv = 1.f / sum;
    const float4* ap = (const float4*)(adj + row);
    float4* op = (float4*)(S + row);
#pragma unroll
    for (int r = 0; r < 3; ++r) {
        float4 a = ap[lane + r * 64];
        float4 o;
        o.x = v[r].x * inv * a.x; o.y = v[r].y * inv * a.y;
        o.z = v[r].z * inv * a.z; o.w = v[r].w * inv * a.w;
        op[lane + r * 64] = o;
    }
}

// ---------------------------------------------------------------------------
// Time attention: per (b,n): attn_t[i,j] = softmax_j(SCALE*<tq_i,tk_j> + Bt[i,j])
// tq/tk: [B, N, T, 64] h-contiguous. One 192-thread block per (b,n).
// ---------------------------------------------------------------------------
__global__ __launch_bounds__(192) void time_attn(const float* __restrict__ TQ,
                                                 const float* __restrict__ TK,
                                                 const float* __restrict__ Bt,
                                                 float* __restrict__ AT)
{
    int bn = blockIdx.x;
    __shared__ float tqs[nT * 64], tks[nT * 64], ss[nT * nT];
    __shared__ float inv_s[nT], max_s[nT];
    int tid = threadIdx.x;
#pragma unroll
    for (int r = 0; r < 4; ++r) {
        int idx = tid + r * 192;
        tqs[idx] = TQ[(size_t)bn * nT * 64 + idx];
        tks[idx] = TK[(size_t)bn * nT * 64 + idx];
    }
    __syncthreads();
    if (tid < 144) {
        int i = tid / 12, j = tid % 12;
        float s = 0.f;
#pragma unroll
        for (int h = 0; h < 64; ++h) s += tqs[i * 64 + h] * tks[j * 64 + h];
        ss[tid] = s * SCALE + Bt[i * 12 + j];
    }
    __syncthreads();
    if (tid < 12) {
        float mx = -1e30f;
        for (int j = 0; j < 12; ++j) mx = fmaxf(mx, ss[tid * 12 + j]);
        float sm = 0.f;
        for (int j = 0; j < 12; ++j) sm += expf(ss[tid * 12 + j] - mx);
        max_s[tid] = mx; inv_s[tid] = 1.f / sm;
    }
    __syncthreads();
    if (tid < 144) {
        int i = tid / 12;
        AT[(size_t)bn * 144 + tid] = expf(ss[tid] - max_s[i]) * inv_s[i];
    }
}

// ---------------------------------------------------------------------------
// Node aggregation: hs[c, w] = sum_v v1t[bl, v, c] * A[bl, v, w]
// Written to H channels [64,128): H[((b*128+64+c)*N + w)*T + l].
// Tile 64c x 64w, K = 768 in chunks of 64.
// ---------------------------------------------------------------------------
__global__ __launch_bounds__(256) void node_agg(const float* __restrict__ V1T,
                                                const float* __restrict__ A,
                                                float* __restrict__ H)
{
    __shared__ __align__(16) float Vs[64][68];  // [v][c]
    __shared__ __align__(16) float Aw[64][68];  // [v][w]
    int tid = threadIdx.x;
    int w0 = blockIdx.x * 64;
    int bl = blockIdx.y;
    int b = bl / nT, l = bl % nT;
    float acc[4][4] = {};
    int cbase = (tid >> 4) * 4, wbase = (tid & 15) * 4;
    for (int v0 = 0; v0 < nN; v0 += 64) {
        {
            int cc = tid & 63, vv = tid >> 6;
#pragma unroll
            for (int r = 0; r < 16; ++r) {
                int v = vv + r * 4;
                Vs[v][cc] = V1T[((size_t)bl * nN + v0 + v) * 64 + cc];
            }
        }
        {
            int ww = tid & 63, vv = tid >> 6;
#pragma unroll
            for (int r = 0; r < 16; ++r) {
                int v = vv + r * 4;
                Aw[v][ww] = A[((size_t)bl * nN + v0 + v) * nN + w0 + ww];
            }
        }
        __syncthreads();
#pragma unroll
        for (int v = 0; v < 64; ++v) {
            float4 av = *(const float4*)&Vs[v][cbase];
            float4 bv = *(const float4*)&Aw[v][wbase];
            float a[4] = {av.x, av.y, av.z, av.w};
            float c[4] = {bv.x, bv.y, bv.z, bv.w};
#pragma unroll
            for (int i = 0; i < 4; ++i)
#pragma unroll
                for (int j = 0; j < 4; ++j) acc[i][j] += a[i] * c[j];
        }
        __syncthreads();
    }
#pragma unroll
    for (int i = 0; i < 4; ++i)
#pragma unroll
        for (int j = 0; j < 4; ++j) {
            int c = cbase + i, w = w0 + wbase + j;
            H[(((size_t)b * 128 + 64 + c) * nN + w) * nT + l] = acc[i][j];
        }
}

// ---------------------------------------------------------------------------
// Time aggregation: ht[b,c,n,t] = sum_v v1t[b,v,n,c] * attn_t[b,n,v,t]
// Written to H channels [0,64). Block 256 = 64c x 4n.
// ---------------------------------------------------------------------------
__global__ __launch_bounds__(256) void time_agg(const float* __restrict__ V1T,
                                                const float* __restrict__ AT,
                                                float* __restrict__ H)
{
    int tid = threadIdx.x;
    int c = tid & 63, nn = tid >> 6;
    int n = blockIdx.x * 4 + nn;
    int b = blockIdx.y;
    float acc[nT] = {};
#pragma unroll
    for (int v = 0; v < nT; ++v) {
        float val = V1T[(((size_t)b * nT + v) * nN + n) * 64 + c];
        const float* at = AT + ((size_t)b * nN + n) * nT * nT + v * nT;
#pragma unroll
        for (int t = 0; t < nT; ++t) acc[t] += val * at[t];
    }
    float* out = H + (((size_t)b * 128 + c) * nN + n) * nT;
#pragma unroll
    for (int t = 0; t < nT; ++t) out[t] = acc[t];
}

// ---------------------------------------------------------------------------
// Channels-first conv1x1 GEMM: OUT[b,o,m] = sum_k W[o,k]*X[b,k,m] + bias[o]
// MODE 0: plain. MODE 1: + RES[b,o,m]. MODE 2: X replaced by X*X2, + RES.
// Tile 64o x 64m, K-chunk 32. Block 256, 4x4 microtile, float4 LDS reads.
// ---------------------------------------------------------------------------
template <int MODE>
__global__ __launch_bounds__(256) void convgemm_cf(const float* __restrict__ X,
                                                   const float* __restrict__ X2,
                                                   const float* __restrict__ W,
                                                   const float* __restrict__ bias,
                                                   const float* __restrict__ RES,
                                                   float* __restrict__ OUT,
                                                   int K, int Cout)
{
    __shared__ __align__(16) float Xs[32][68];
    __shared__ __align__(16) float Ws[32][68];  // [k][o]
    int tid = threadIdx.x;
    int m0 = blockIdx.x * 64, o0 = blockIdx.y * 64, b = blockIdx.z;
    const float* Xb = X + (size_t)b * K * nM;
    const float* X2b = (MODE == 2) ? X2 + (size_t)b * K * nM : nullptr;
    float acc[4][4] = {};
    int obase = (tid >> 4) * 4, mbase = (tid & 15) * 4;
    for (int k0 = 0; k0 < K; k0 += 32) {
        {
            int m = tid & 63, kk = tid >> 6;
#pragma unroll
            for (int r = 0; r < 8; ++r) {
                int k = kk + r * 4;
                size_t gi = (size_t)(k0 + k) * nM + m0 + m;
                float xv = Xb[gi];
                if (MODE == 2) xv *= X2b[gi];
                Xs[k][m] = xv;
            }
        }
        {
            int k = tid & 31, oo = tid >> 5;
#pragma unroll
            for (int r = 0; r < 8; ++r) {
                int o = oo + r * 8;
                Ws[k][o] = W[(size_t)(o0 + o) * K + k0 + k];
            }
        }
        __syncthreads();
#pragma unroll
        for (int k = 0; k < 32; ++k) {
            float4 av = *(const float4*)&Ws[k][obase];
            float4 bv = *(const float4*)&Xs[k][mbase];
            float a[4] = {av.x, av.y, av.z, av.w};
            float c[4] = {bv.x, bv.y, bv.z, bv.w};
#pragma unroll
            for (int i = 0; i < 4; ++i)
#pragma unroll
                for (int j = 0; j < 4; ++j) acc[i][j] += a[i] * c[j];
        }
        __syncthreads();
    }
#pragma unroll
    for (int i = 0; i < 4; ++i) {
        int o = o0 + obase + i;
        size_t rowoff = ((size_t)b * Cout + o) * nM + m0 + mbase;
        float bb = bias[o];
        float4 o4;
        o4.x = acc[i][0] + bb; o4.y = acc[i][1] + bb;
        o4.z = acc[i][2] + bb; o4.w = acc[i][3] + bb;
        if (MODE >= 1) {
            float4 rr = *(const float4*)&RES[rowoff];
            o4.x += rr.x; o4.y += rr.y; o4.z += rr.z; o4.w += rr.w;
        }
        *(float4*)&OUT[rowoff] = o4;
    }
}

// ---------------------------------------------------------------------------
// FFN1 with gating: OUT[b,o,m] = (A + b1[o]) * gelu(G + b1[o+512]),
// A = sum_k W1[o,k]*X, G = sum_k W1[o+512,k]*X, o in [0,512). Exact GELU.
// ---------------------------------------------------------------------------
__global__ __launch_bounds__(256) void ffn1_gated(const float* __restrict__ X,
                                                  const float* __restrict__ W1,
                                                  const float* __restrict__ B1,
                                                  float* __restrict__ OUT)
{
    __shared__ __align__(16) float Xs[32][68];
    __shared__ __align__(16) float Wa[32][68];
    __shared__ __align__(16) float Wg[32][68];
    int tid = threadIdx.x;
    int m0 = blockIdx.x * 64, o0 = blockIdx.y * 64, b = blockIdx.z;
    const float* Xb = X + (size_t)b * nC * nM;
    float acca[4][4] = {}, accg[4][4] = {};
    int obase = (tid >> 4) * 4, mbase = (tid & 15) * 4;
    for (int k0 = 0; k0 < nC; k0 += 32) {
        {
            int m = tid & 63, kk = tid >> 6;
#pragma unroll
            for (int r = 0; r < 8; ++r) {
                int k = kk + r * 4;
                Xs[k][m] = Xb[(size_t)(k0 + k) * nM + m0 + m];
            }
        }
        {
            int k = tid & 31, oo = tid >> 5;
#pragma unroll
            for (int r = 0; r < 8; ++r) {
                int o = oo + r * 8;
                Wa[k][o] = W1[(size_t)(o0 + o) * nC + k0 + k];
                Wg[k][o] = W1[(size_t)(512 + o0 + o) * nC + k0 + k];
            }
        }
        __syncthreads();
#pragma unroll
        for (int k = 0; k < 32; ++k) {
            float4 av = *(const float4*)&Wa[k][obase];
            float4 gv = *(const float4*)&Wg[k][obase];
            float4 bv = *(const float4*)&Xs[k][mbase];
            float a[4] = {av.x, av.y, av.z, av.w};
            float g[4] = {gv.x, gv.y, gv.z, gv.w};
            float c[4] = {bv.x, bv.y, bv.z, bv.w};
#pragma unroll
            for (int i = 0; i < 4; ++i)
#pragma unroll
                for (int j = 0; j < 4; ++j) {
                    acca[i][j] += a[i] * c[j];
                    accg[i][j] += g[i] * c[j];
                }
        }
        __syncthreads();
    }
#pragma unroll
    for (int i = 0; i < 4; ++i) {
        int o = o0 + obase + i;
        float ba = B1[o], bg = B1[512 + o];
        float vals[4];
#pragma unroll
        for (int j = 0; j < 4; ++j) {
            float a = acca[i][j] + ba;
            float g = accg[i][j] + bg;
            float gl = 0.5f * g * (1.f + erff(g * 0.70710678118654752f));
            vals[j] = a * gl;
        }
        float4 o4; o4.x = vals[0]; o4.y = vals[1]; o4.z = vals[2]; o4.w = vals[3];
        *(float4*)&OUT[((size_t)b * 512 + o) * nM + m0 + mbase] = o4;
    }
}

// ---------------------------------------------------------------------------
extern "C" void kernel_launch(void* const* d_in, const int* in_sizes, int n_in,
                              void* d_out, int out_size, void* d_ws, size_t ws_size,
                              hipStream_t stream)
{
    const float* x      = (const float*)d_in[0];
    // d_in[1..3]: time_ind / weekin / holiin — unused by the reference
    const float* adj    = (const float*)d_in[4];
    const float* ln1w   = (const float*)d_in[5];
    const float* ln1b   = (const float*)d_in[6];
    const float* ln2w   = (const float*)d_in[7];
    const float* ln2b   = (const float*)d_in[8];
    const float* Wnq    = (const float*)d_in[9];
    const float* bnq    = (const float*)d_in[10];
    const float* Wnk    = (const float*)d_in[11];
    const float* bnk    = (const float*)d_in[12];
    const float* Wtq    = (const float*)d_in[13];
    const float* btq    = (const float*)d_in[14];
    const float* Wtk    = (const float*)d_in[15];
    const float* btk    = (const float*)d_in[16];
    const float* Bn     = (const float*)d_in[17];
    const float* Bt     = (const float*)d_in[18];
    const float* v_w    = (const float*)d_in[19];
    const float* v_b    = (const float*)d_in[20];
    const float* fcv_w  = (const float*)d_in[21];
    const float* fcv_b  = (const float*)d_in[22];
    const float* proj_w = (const float*)d_in[23];
    const float* proj_b = (const float*)d_in[24];
    const float* w1     = (const float*)d_in[25];
    const float* b1     = (const float*)d_in[26];
    const float* w2     = (const float*)d_in[27];
    const float* b2     = (const float*)d_in[28];
    float* out = (float*)d_out;

    // Workspace layout (floats). Total 109,412,352 floats = 437.7 MB.
    float* ws   = (float*)d_ws;
    float* x1   = ws;                                   // [B,256,M]   18,874,368
    float* nq   = x1 + (size_t)nB * nC * nM;            // [B*T,N,64]   4,718,592
    float* nk   = nq + (size_t)nB * nT * nN * 64;       //              4,718,592
    float* Dbuf = nk + (size_t)nB * nT * nN * 64;       // [B*T,N,N]   56,623,104
    float* atT  = Dbuf + (size_t)nB * nT * nN * nN;     // [B,N,T,T]      884,736
    float* v1t  = atT + (size_t)nB * nN * nT * nT;      // [B,T,N,64]   4,718,592
    float* hbuf = v1t + (size_t)nB * nT * nN * 64;      // [B,128,M]    9,437,184
    float* vg   = hbuf + (size_t)nB * 128 * nM;         // [B,128,M]    9,437,184
    float* xr   = x1;                // reuse: x1 dead after fcv
    float* x2   = Dbuf;              // reuse: attn_n dead after node_agg
    float* g1   = Dbuf + (size_t)nB * nC * nM;          // [B,512,M]   37,748,736

    dim3 blk(256);

    // 1. LN1
    ln_cf<<<dim3(144, nB), blk, 0, stream>>>(x, ln1w, ln1b, x1);
    // 2-3. node q/k projections ([B,T,N,64])
    convgemm_cl<true, false><<<dim3(144, nB), blk, 0, stream>>>(x1, Wnq, bnq, nq);
    convgemm_cl<true, false><<<dim3(144, nB), blk, 0, stream>>>(x1, Wnk, bnk, nk);
    // 4. node scores -> Dbuf
    node_scores<<<dim3(12, 12, nB * nT), blk, 0, stream>>>(nq, nk, Bn, Dbuf);
    // 5. softmax * adj, in-place
    softmax_adj<<<dim3(192, nB * nT), blk, 0, stream>>>(Dbuf, adj);
    // 6-7. time q/k projections ([B,N,T,64]) — reuse nq/nk
    convgemm_cl<false, false><<<dim3(144, nB), blk, 0, stream>>>(x1, Wtq, btq, nq);
    convgemm_cl<false, false><<<dim3(144, nB), blk, 0, stream>>>(x1, Wtk, btk, nk);
    // 8. time attention -> atT
    time_attn<<<dim3(nB * nN), dim3(192), 0, stream>>>(nq, nk, Bt, atT);
    // 9. v1 in [B,T,N,64] layout
    convgemm_cl<true, true><<<dim3(144, nB), blk, 0, stream>>>(x1, v_w, v_b, v1t);
    // 10. node aggregation -> hbuf channels [64,128)
    node_agg<<<dim3(12, nB * nT), blk, 0, stream>>>(v1t, Dbuf, hbuf);
    // 11. time aggregation -> hbuf channels [0,64)
    time_agg<<<dim3(192, nB), blk, 0, stream>>>(v1t, atT, hbuf);
    // 12. vg = fcv(x1)
    convgemm_cf<0><<<dim3(144, 2, nB), blk, 0, stream>>>(x1, nullptr, fcv_w, fcv_b,
                                                         nullptr, vg, nC, 128);
    // 13. xr = proj(h*vg) + x   (overwrites x1, which is now dead)
    convgemm_cf<2><<<dim3(144, 4, nB), blk, 0, stream>>>(hbuf, vg, proj_w, proj_b,
                                                         x, xr, 128, nC);
    // 14. LN2 -> x2
    ln_cf<<<dim3(144, nB), blk, 0, stream>>>(xr, ln2w, ln2b, x2);
    // 15. FFN1 gated -> g1
    ffn1_gated<<<dim3(144, 8, nB), blk, 0, stream>>>(x2, w1, b1, g1);
    // 16. FFN2 + residual -> out
    convgemm_cf<1><<<dim3(144, 4, nB), blk, 0, stream>>>(g1, nullptr, w2, b2,
                                                         xr, out, 512, nC);
}

// Round 2
// 983.198 us; speedup vs baseline: 1.9609x; 1.9609x over previous
//
#include <hip/hip_runtime.h>
#include <cstddef>

typedef unsigned short u16;
typedef __attribute__((ext_vector_type(8))) short bf16x8;
typedef __attribute__((ext_vector_type(4))) float f32x4;

constexpr int nB = 8, nC = 256, nN = 768, nT = 12, nM = nN * nT, nH = 64;
constexpr float SCALE = 0.125f;
constexpr float LNEPS = 1e-6f;

// ---------------- bf16 helpers ----------------
__device__ inline u16 f2b(float f) {
    union { float f; unsigned u; } v; v.f = f;
    unsigned r = v.u + 0x7FFFu + ((v.u >> 16) & 1u);
    return (u16)(r >> 16);
}
__device__ inline float b2f(u16 h) {
    union { unsigned u; float f; } v; v.u = ((unsigned)h) << 16;
    return v.f;
}
__device__ inline uint2 packb4(float a, float b, float c, float d) {
    uint2 r;
    r.x = (unsigned)f2b(a) | ((unsigned)f2b(b) << 16);
    r.y = (unsigned)f2b(c) | ((unsigned)f2b(d) << 16);
    return r;
}
__device__ inline f32x4 mfma16(bf16x8 a, bf16x8 b, f32x4 c) {
    return __builtin_amdgcn_mfma_f32_16x16x32_bf16(a, b, c, 0, 0, 0);
}

// Stage a 64x64 bf16 tile (row stride ld elements) into LDS [64][72].
__device__ inline void stage64(const u16* __restrict__ g, int ld, u16* lds, int tid) {
#pragma unroll
    for (int r = 0; r < 2; ++r) {
        int c = tid + r * 256;
        int row = c >> 3, kc = (c & 7) * 8;
        *(uint4*)&lds[row * 72 + kc] = *(const uint4*)&g[(size_t)row * ld + kc];
    }
}

// One 64-wide K-chunk of MFMA compute. acc[2][2] over (o-sub, m-sub) 16x16 tiles.
__device__ inline void mfma_block(const u16* As, const u16* Bs, f32x4 acc[2][2],
                                  int wo, int wm, int quad, int r) {
#pragma unroll
    for (int ks = 0; ks < 64; ks += 32) {
        bf16x8 a0 = *(const bf16x8*)&As[(wo + r) * 72 + ks + quad * 8];
        bf16x8 a1 = *(const bf16x8*)&As[(wo + 16 + r) * 72 + ks + quad * 8];
        bf16x8 b0 = *(const bf16x8*)&Bs[(wm + r) * 72 + ks + quad * 8];
        bf16x8 b1 = *(const bf16x8*)&Bs[(wm + 16 + r) * 72 + ks + quad * 8];
        acc[0][0] = mfma16(a0, b0, acc[0][0]);
        acc[0][1] = mfma16(a0, b1, acc[0][1]);
        acc[1][0] = mfma16(a1, b0, acc[1][0]);
        acc[1][1] = mfma16(a1, b1, acc[1][1]);
    }
}

// ---------------- weight conversion (fp32 -> bf16, with q/k transposes) ------
// Layout in WB (u16): wq@0 wk@16384 wtq@32768 wtk@49152 wv@65536 wfcv@81920
//                     wproj@114688 wf1@147456 wf2@409600, total 540672
__global__ __launch_bounds__(256) void cvt_w(const float* __restrict__ Wnq,
                                             const float* __restrict__ Wnk,
                                             const float* __restrict__ Wtq,
                                             const float* __restrict__ Wtk,
                                             const float* __restrict__ vw,
                                             const float* __restrict__ fcvw,
                                             const float* __restrict__ projw,
                                             const float* __restrict__ w1,
                                             const float* __restrict__ w2,
                                             u16* __restrict__ WB) {
    int i = blockIdx.x * 256 + threadIdx.x;
    float v;
    if (i < 65536) {
        int seg = i >> 14, j = i & 16383;
        int o = j >> 8, k = j & 255;
        const float* src = seg == 0 ? Wnq : seg == 1 ? Wnk : seg == 2 ? Wtq : Wtk;
        v = src[k * 64 + o];                       // [c][h] -> [h][c]
    } else if (i < 81920)  v = vw[i - 65536];
    else if (i < 114688)   v = fcvw[i - 81920];
    else if (i < 147456)   v = projw[i - 114688];
    else if (i < 409600)   v = w1[i - 147456];
    else                   v = w2[i - 409600];
    WB[i] = f2b(v);
}

__global__ __launch_bounds__(256) void zero_f(float* __restrict__ p) {
    p[blockIdx.x * 256 + threadIdx.x] = 0.f;
}

// ---------------- LayerNorm (channels-first fp32 in, channels-last bf16 out) --
__global__ __launch_bounds__(256) void ln_cl(const float* __restrict__ X,
                                             const float* __restrict__ w,
                                             const float* __restrict__ bias,
                                             u16* __restrict__ Y) {
    int tid = threadIdx.x;
    int lane = tid & 63, cg = tid >> 6;
    int m0 = blockIdx.x * 64, b = blockIdx.y;
    size_t base = (size_t)b * nC * nM + m0 + lane;
    float s = 0.f, ss = 0.f;
#pragma unroll 4
    for (int k = 0; k < 64; ++k) {
        float v = X[base + (size_t)(cg * 64 + k) * nM];
        s += v; ss += v * v;
    }
    __shared__ float rs[4][64], rss[4][64], mu_s[64], rstd_s[64];
    __shared__ u16 Lo[64][264];
    rs[cg][lane] = s; rss[cg][lane] = ss;
    __syncthreads();
    if (tid < 64) {
        float t1 = rs[0][lane] + rs[1][lane] + rs[2][lane] + rs[3][lane];
        float t2 = rss[0][lane] + rss[1][lane] + rss[2][lane] + rss[3][lane];
        float mu = t1 * (1.f / nC);
        float var = t2 * (1.f / nC) - mu * mu;
        mu_s[lane] = mu;
        rstd_s[lane] = rsqrtf(var + LNEPS);
    }
    __syncthreads();
    float mu = mu_s[lane], rstd = rstd_s[lane];
#pragma unroll 8
    for (int k = 0; k < 64; k += 2) {
        int c = cg * 64 + k;
        float v0 = (X[base + (size_t)c * nM] - mu) * rstd * w[c] + bias[c];
        float v1 = (X[base + (size_t)(c + 1) * nM] - mu) * rstd * w[c + 1] + bias[c + 1];
        *(unsigned*)&Lo[lane][c] = (unsigned)f2b(v0) | ((unsigned)f2b(v1) << 16);
    }
    __syncthreads();
#pragma unroll
    for (int r = 0; r < 8; ++r) {
        int c = tid + r * 256;
        int mm = c >> 5, ch = (c & 31) * 8;
        *(uint4*)&Y[((size_t)b * nM + m0 + mm) * 256 + ch] = *(uint4*)&Lo[mm][ch];
    }
}

// ---------------- generic projection GEMM (X channels-last, K=256) ----------
// LAYOUT 0: OUT[(b*12+t)][n][COUT] (nq/nk)   1: OUT[b][m][COUT] (tq/tk/fcv)
//        2: OUT[(b*12+t)][o][n] (v1)
template <int COUT, int LAYOUT>
__global__ __launch_bounds__(256) void gemm_proj(const u16* __restrict__ X,
                                                 const u16* __restrict__ W,
                                                 const float* __restrict__ bias,
                                                 u16* __restrict__ OUT) {
    __shared__ u16 As[64 * 72], Bs[64 * 72];
    int tid = threadIdx.x;
    int m0 = blockIdx.x * 64, o0 = blockIdx.y * 64, b = blockIdx.z;
    int lane = tid & 63, wid = tid >> 6;
    int wo = (wid & 1) * 32, wm = (wid >> 1) * 32;
    int quad = lane >> 4, r = lane & 15;
    const u16* Ag = W + (size_t)o0 * 256;
    const u16* Bg = X + ((size_t)b * nM + m0) * 256;
    f32x4 acc[2][2] = {};
    for (int k0 = 0; k0 < 256; k0 += 64) {
        __syncthreads();
        stage64(Ag + k0, 256, As, tid);
        stage64(Bg + k0, 256, Bs, tid);
        __syncthreads();
        mfma_block(As, Bs, acc, wo, wm, quad, r);
    }
#pragma unroll
    for (int oi = 0; oi < 2; ++oi)
#pragma unroll
        for (int mj = 0; mj < 2; ++mj) {
            int o = o0 + wo + oi * 16 + quad * 4;
            int m = m0 + wm + mj * 16 + r;
            f32x4 a = acc[oi][mj];
            float v0 = a[0] + bias[o], v1 = a[1] + bias[o + 1];
            float v2 = a[2] + bias[o + 2], v3 = a[3] + bias[o + 3];
            if (LAYOUT == 1) {
                *(uint2*)&OUT[((size_t)b * nM + m) * COUT + o] = packb4(v0, v1, v2, v3);
            } else if (LAYOUT == 0) {
                int n = m / 12, t = m - n * 12;
                *(uint2*)&OUT[((size_t)(b * 12 + t) * nN + n) * COUT + o] =
                    packb4(v0, v1, v2, v3);
            } else {
                int n = m / 12, t = m - n * 12;
                size_t bt = (size_t)(b * 12 + t) * 64;
                OUT[(bt + o) * nN + n]     = f2b(v0);
                OUT[(bt + o + 1) * nN + n] = f2b(v1);
                OUT[(bt + o + 2) * nN + n] = f2b(v2);
                OUT[(bt + o + 3) * nN + n] = f2b(v3);
            }
        }
}

// ---------------- node scores: SE = exp(scale*qk + Bn), + row sums ----------
__global__ __launch_bounds__(256) void scores_k(const u16* __restrict__ NQ,
                                                const u16* __restrict__ NK,
                                                const float* __restrict__ Bn,
                                                u16* __restrict__ SE,
                                                float* __restrict__ rowsum) {
    __shared__ u16 As[64 * 72], Bs[64 * 72];
    __shared__ float lsum[64];
    int tid = threadIdx.x;
    int j0 = blockIdx.x * 64, i0 = blockIdx.y * 64, bt = blockIdx.z;
    if (tid < 64) lsum[tid] = 0.f;
    int lane = tid & 63, wid = tid >> 6;
    int wo = (wid & 1) * 32, wm = (wid >> 1) * 32;
    int quad = lane >> 4, r = lane & 15;
    const u16* Ag = NQ + ((size_t)bt * nN + i0) * 64;
    const u16* Bg = NK + ((size_t)bt * nN + j0) * 64;
    f32x4 acc[2][2] = {};
    __syncthreads();
    stage64(Ag, 64, As, tid);
    stage64(Bg, 64, Bs, tid);
    __syncthreads();
    mfma_block(As, Bs, acc, wo, wm, quad, r);
#pragma unroll
    for (int oi = 0; oi < 2; ++oi) {
        f32x4 rsm = {0.f, 0.f, 0.f, 0.f};
#pragma unroll
        for (int mj = 0; mj < 2; ++mj) {
            int i_ = i0 + wo + oi * 16 + quad * 4;
            int j_ = j0 + wm + mj * 16 + r;
#pragma unroll
            for (int rr = 0; rr < 4; ++rr) {
                float s = acc[oi][mj][rr] * SCALE + Bn[(size_t)(i_ + rr) * nN + j_];
                float e = expf(s);
                SE[((size_t)bt * nN + i_ + rr) * nN + j_] = f2b(e);
                rsm[rr] += e;
            }
        }
#pragma unroll
        for (int mask = 1; mask < 16; mask <<= 1) {
            rsm[0] += __shfl_xor(rsm[0], mask);
            rsm[1] += __shfl_xor(rsm[1], mask);
            rsm[2] += __shfl_xor(rsm[2], mask);
            rsm[3] += __shfl_xor(rsm[3], mask);
        }
        if (r == 0) {
#pragma unroll
            for (int rr = 0; rr < 4; ++rr)
                atomicAdd(&lsum[wo + oi * 16 + quad * 4 + rr], rsm[rr]);
        }
    }
    __syncthreads();
    if (tid < 64) atomicAdd(&rowsum[(size_t)bt * nN + i0 + tid], lsum[tid]);
}

// ---------------- attn finalize + transpose: AT2[w][v] = SE[v][w]*adj/rowsum --
__global__ __launch_bounds__(256) void attn_fin(const u16* __restrict__ SE,
                                                const float* __restrict__ adj,
                                                const float* __restrict__ rowsum,
                                                u16* __restrict__ AT2) {
    __shared__ u16 Ls[64 * 72];
    __shared__ float rinv[64];
    int tid = threadIdx.x;
    int w0 = blockIdx.x * 64, v0 = blockIdx.y * 64, bt = blockIdx.z;
    if (tid < 64) rinv[tid] = 1.f / rowsum[(size_t)bt * nN + v0 + tid];
    __syncthreads();
    {
        int v = tid >> 2, wc = (tid & 3) * 16;
        const u16* se = SE + ((size_t)bt * nN + v0 + v) * nN + w0 + wc;
        const float* ad = adj + ((size_t)bt * nN + v0 + v) * nN + w0 + wc;
        float ri = rinv[v];
        union { uint4 q; u16 s[8]; } p0, p1;
#pragma unroll
        for (int ii = 0; ii < 8; ++ii) p0.s[ii] = f2b(b2f(se[ii]) * ad[ii] * ri);
#pragma unroll
        for (int ii = 0; ii < 8; ++ii) p1.s[ii] = f2b(b2f(se[8 + ii]) * ad[8 + ii] * ri);
        *(uint4*)&Ls[v * 72 + wc] = p0.q;
        *(uint4*)&Ls[v * 72 + wc + 8] = p1.q;
    }
    __syncthreads();
    {
        int w = tid >> 2, vc = (tid & 3) * 16;
        union { uint4 q; u16 s[8]; } p0, p1;
#pragma unroll
        for (int ii = 0; ii < 8; ++ii) p0.s[ii] = Ls[(vc + ii) * 72 + w];
#pragma unroll
        for (int ii = 0; ii < 8; ++ii) p1.s[ii] = Ls[(vc + 8 + ii) * 72 + w];
        u16* op = AT2 + ((size_t)bt * nN + w0 + w) * nN + v0 + vc;
        *(uint4*)&op[0] = p0.q;
        *(uint4*)&op[8] = p1.q;
    }
}

// ---------------- node aggregation: hs[c][w] = sum_v v1n[c][v] * AT2[w][v] ---
__global__ __launch_bounds__(256) void node_agg_k(const u16* __restrict__ V1N,
                                                  const u16* __restrict__ AT2,
                                                  u16* __restrict__ HB) {
    __shared__ u16 As[64 * 72], Bs[64 * 72];
    int tid = threadIdx.x;
    int w0 = blockIdx.x * 64, bt = blockIdx.z;
    int b = bt / 12, l = bt - b * 12;
    int lane = tid & 63, wid = tid >> 6;
    int wo = (wid & 1) * 32, wm = (wid >> 1) * 32;
    int quad = lane >> 4, r = lane & 15;
    const u16* Ag = V1N + (size_t)bt * 64 * nN;
    const u16* Bg = AT2 + ((size_t)bt * nN + w0) * nN;
    f32x4 acc[2][2] = {};
    for (int k0 = 0; k0 < nN; k0 += 64) {
        __syncthreads();
        stage64(Ag + k0, nN, As, tid);
        stage64(Bg + k0, nN, Bs, tid);
        __syncthreads();
        mfma_block(As, Bs, acc, wo, wm, quad, r);
    }
#pragma unroll
    for (int oi = 0; oi < 2; ++oi)
#pragma unroll
        for (int mj = 0; mj < 2; ++mj) {
            int c = wo + oi * 16 + quad * 4;
            int w = w0 + wm + mj * 16 + r;
            f32x4 a = acc[oi][mj];
            *(uint2*)&HB[((size_t)b * nM + w * 12 + l) * 128 + 64 + c] =
                packb4(a[0], a[1], a[2], a[3]);
        }
}

// ---------------- time attention (tiny) -------------------------------------
__global__ __launch_bounds__(192) void time_attn(const u16* __restrict__ TQ,
                                                 const u16* __restrict__ TK,
                                                 const float* __restrict__ Bt,
                                                 float* __restrict__ AT) {
    int bn = blockIdx.x;  // b*768 + n
    __shared__ float tqs[nT * 64], tks[nT * 64], ss[nT * nT];
    __shared__ float inv_s[nT], max_s[nT];
    int tid = threadIdx.x;
    size_t base = (size_t)bn * nT * 64;
#pragma unroll
    for (int r = 0; r < 4; ++r) {
        int idx = tid + r * 192;
        tqs[idx] = b2f(TQ[base + idx]);
        tks[idx] = b2f(TK[base + idx]);
    }
    __syncthreads();
    if (tid < 144) {
        int i = tid / 12, j = tid % 12;
        float s = 0.f;
#pragma unroll
        for (int h = 0; h < 64; ++h) s += tqs[i * 64 + h] * tks[j * 64 + h];
        ss[tid] = s * SCALE + Bt[i * 12 + j];
    }
    __syncthreads();
    if (tid < 12) {
        float mx = -1e30f;
        for (int j = 0; j < 12; ++j) mx = fmaxf(mx, ss[tid * 12 + j]);
        float sm = 0.f;
        for (int j = 0; j < 12; ++j) sm += expf(ss[tid * 12 + j] - mx);
        max_s[tid] = mx; inv_s[tid] = 1.f / sm;
    }
    __syncthreads();
    if (tid < 144) {
        int i = tid / 12;
        AT[(size_t)bn * 144 + tid] = expf(ss[tid] - max_s[i]) * inv_s[i];
    }
}

// ---------------- time aggregation ------------------------------------------
__global__ __launch_bounds__(256) void time_agg_k(const u16* __restrict__ V1N,
                                                  const float* __restrict__ AT,
                                                  u16* __restrict__ HB) {
    int tid = threadIdx.x;
    int lane = tid & 63, cg = tid >> 6;
    int n = blockIdx.x * 64 + lane;
    int b = blockIdx.y;
    size_t bn = (size_t)b * nN + n;
#pragma unroll 2
    for (int cc = 0; cc < 16; ++cc) {
        int c = cg * 16 + cc;
        float acc[12] = {};
        for (int v = 0; v < 12; ++v) {
            float val = b2f(V1N[((size_t)(b * 12 + v) * 64 + c) * nN + n]);
            const float4* at4 = (const float4*)(AT + bn * 144 + v * 12);
            float4 a0 = at4[0], a1 = at4[1], a2 = at4[2];
            acc[0] += val * a0.x;  acc[1] += val * a0.y;
            acc[2] += val * a0.z;  acc[3] += val * a0.w;
            acc[4] += val * a1.x;  acc[5] += val * a1.y;
            acc[6] += val * a1.z;  acc[7] += val * a1.w;
            acc[8] += val * a2.x;  acc[9] += val * a2.y;
            acc[10] += val * a2.z; acc[11] += val * a2.w;
        }
#pragma unroll
        for (int t = 0; t < 12; ++t)
            HB[((size_t)b * nM + n * 12 + t) * 128 + c] = f2b(acc[t]);
    }
}

// ---------------- proj GEMM on (h .* vg), channels-first fp32 out + residual -
__global__ __launch_bounds__(256) void prodproj_k(const u16* __restrict__ HB,
                                                  const u16* __restrict__ VG,
                                                  const u16* __restrict__ W,
                                                  const float* __restrict__ bias,
                                                  const float* __restrict__ RES,
                                                  float* __restrict__ OUT) {
    __shared__ u16 As[64 * 72], Bs[64 * 72];
    int tid = threadIdx.x;
    int m0 = blockIdx.x * 64, o0 = blockIdx.y * 64, b = blockIdx.z;
    int lane = tid & 63, wid = tid >> 6;
    int wo = (wid & 1) * 32, wm = (wid >> 1) * 32;
    int quad = lane >> 4, r = lane & 15;
    f32x4 acc[2][2] = {};
    for (int k0 = 0; k0 < 128; k0 += 64) {
        __syncthreads();
        stage64(W + (size_t)o0 * 128 + k0, 128, As, tid);
#pragma unroll
        for (int rr = 0; rr < 2; ++rr) {
            int c = tid + rr * 256;
            int row = c >> 3, kc = (c & 7) * 8;
            size_t gi = ((size_t)b * nM + m0 + row) * 128 + k0 + kc;
            uint4 hv = *(const uint4*)&HB[gi];
            uint4 vv = *(const uint4*)&VG[gi];
            u16* hs = (u16*)&hv; u16* vs = (u16*)&vv;
            union { uint4 q; u16 s[8]; } ov;
#pragma unroll
            for (int q2 = 0; q2 < 8; ++q2) ov.s[q2] = f2b(b2f(hs[q2]) * b2f(vs[q2]));
            *(uint4*)&Bs[row * 72 + kc] = ov.q;
        }
        __syncthreads();
        mfma_block(As, Bs, acc, wo, wm, quad, r);
    }
#pragma unroll
    for (int oi = 0; oi < 2; ++oi)
#pragma unroll
        for (int mj = 0; mj < 2; ++mj) {
            int o = o0 + wo + oi * 16 + quad * 4;
            int m = m0 + wm + mj * 16 + r;
            f32x4 a = acc[oi][mj];
#pragma unroll
            for (int rr = 0; rr < 4; ++rr) {
                size_t idx = ((size_t)(b * nC + o + rr)) * nM + m;
                OUT[idx] = a[rr] + bias[o + rr] + RES[idx];
            }
        }
}

// ---------------- FFN1 gated (a * gelu(g)) -> bf16 channels-last ------------
__global__ __launch_bounds__(256) void ffn1_k(const u16* __restrict__ X,
                                              const u16* __restrict__ W1,
                                              const float* __restrict__ B1,
                                              u16* __restrict__ G1) {
    __shared__ u16 As[64 * 72], Gs[64 * 72], Bs[64 * 72];
    int tid = threadIdx.x;
    int m0 = blockIdx.x * 64, o0 = blockIdx.y * 64, b = blockIdx.z;
    int lane = tid & 63, wid = tid >> 6;
    int wo = (wid & 1) * 32, wm = (wid >> 1) * 32;
    int quad = lane >> 4, r = lane & 15;
    f32x4 acca[2][2] = {}, accg[2][2] = {};
    for (int k0 = 0; k0 < 256; k0 += 64) {
        __syncthreads();
        stage64(W1 + (size_t)o0 * 256 + k0, 256, As, tid);
        stage64(W1 + (size_t)(512 + o0) * 256 + k0, 256, Gs, tid);
        stage64(X + ((size_t)b * nM + m0) * 256 + k0, 256, Bs, tid);
        __syncthreads();
#pragma unroll
        for (int ks = 0; ks < 64; ks += 32) {
            bf16x8 a0 = *(const bf16x8*)&As[(wo + r) * 72 + ks + quad * 8];
            bf16x8 a1 = *(const bf16x8*)&As[(wo + 16 + r) * 72 + ks + quad * 8];
            bf16x8 g0 = *(const bf16x8*)&Gs[(wo + r) * 72 + ks + quad * 8];
            bf16x8 g1 = *(const bf16x8*)&Gs[(wo + 16 + r) * 72 + ks + quad * 8];
            bf16x8 b0 = *(const bf16x8*)&Bs[(wm + r) * 72 + ks + quad * 8];
            bf16x8 b1 = *(const bf16x8*)&Bs[(wm + 16 + r) * 72 + ks + quad * 8];
            acca[0][0] = mfma16(a0, b0, acca[0][0]);
            acca[0][1] = mfma16(a0, b1, acca[0][1]);
            acca[1][0] = mfma16(a1, b0, acca[1][0]);
            acca[1][1] = mfma16(a1, b1, acca[1][1]);
            accg[0][0] = mfma16(g0, b0, accg[0][0]);
            accg[0][1] = mfma16(g0, b1, accg[0][1]);
            accg[1][0] = mfma16(g1, b0, accg[1][0]);
            accg[1][1] = mfma16(g1, b1, accg[1][1]);
        }
    }
#pragma unroll
    for (int oi = 0; oi < 2; ++oi)
#pragma unroll
        for (int mj = 0; mj < 2; ++mj) {
            int o = o0 + wo + oi * 16 + quad * 4;
            int m = m0 + wm + mj * 16 + r;
            float vals[4];
#pragma unroll
            for (int rr = 0; rr < 4; ++rr) {
                float aa = acca[oi][mj][rr] + B1[o + rr];
                float gg = accg[oi][mj][rr] + B1[512 + o + rr];
                float gl = 0.5f * gg * (1.f + erff(gg * 0.70710678118654752f));
                vals[rr] = aa * gl;
            }
            *(uint2*)&G1[((size_t)b * nM + m) * 512 + o] =
                packb4(vals[0], vals[1], vals[2], vals[3]);
        }
}

// ---------------- FFN2: channels-first fp32 out + residual ------------------
__global__ __launch_bounds__(256) void ffn2_k(const u16* __restrict__ G1,
                                              const u16* __restrict__ W2,
                                              const float* __restrict__ B2,
                                              const float* __restrict__ RES,
                                              float* __restrict__ OUT) {
    __shared__ u16 As[64 * 72], Bs[64 * 72];
    int tid = threadIdx.x;
    int m0 = blockIdx.x * 64, o0 = blockIdx.y * 64, b = blockIdx.z;
    int lane = tid & 63, wid = tid >> 6;
    int wo = (wid & 1) * 32, wm = (wid >> 1) * 32;
    int quad = lane >> 4, r = lane & 15;
    f32x4 acc[2][2] = {};
    for (int k0 = 0; k0 < 512; k0 += 64) {
        __syncthreads();
        stage64(W2 + (size_t)o0 * 512 + k0, 512, As, tid);
        stage64(G1 + ((size_t)b * nM + m0) * 512 + k0, 512, Bs, tid);
        __syncthreads();
        mfma_block(As, Bs, acc, wo, wm, quad, r);
    }
#pragma unroll
    for (int oi = 0; oi < 2; ++oi)
#pragma unroll
        for (int mj = 0; mj < 2; ++mj) {
            int o = o0 + wo + oi * 16 + quad * 4;
            int m = m0 + wm + mj * 16 + r;
            f32x4 a = acc[oi][mj];
#pragma unroll
            for (int rr = 0; rr < 4; ++rr) {
                size_t idx = ((size_t)(b * nC + o + rr)) * nM + m;
                OUT[idx] = a[rr] + B2[o + rr] + RES[idx];
            }
        }
}

// ---------------------------------------------------------------------------
extern "C" void kernel_launch(void* const* d_in, const int* in_sizes, int n_in,
                              void* d_out, int out_size, void* d_ws, size_t ws_size,
                              hipStream_t stream) {
    const float* x      = (const float*)d_in[0];
    const float* adj    = (const float*)d_in[4];
    const float* ln1w   = (const float*)d_in[5];
    const float* ln1b   = (const float*)d_in[6];
    const float* ln2w   = (const float*)d_in[7];
    const float* ln2b   = (const float*)d_in[8];
    const float* Wnq    = (const float*)d_in[9];
    const float* bnq    = (const float*)d_in[10];
    const float* Wnk    = (const float*)d_in[11];
    const float* bnk    = (const float*)d_in[12];
    const float* Wtq    = (const float*)d_in[13];
    const float* btq    = (const float*)d_in[14];
    const float* Wtk    = (const float*)d_in[15];
    const float* btk    = (const float*)d_in[16];
    const float* Bn     = (const float*)d_in[17];
    const float* Bt     = (const float*)d_in[18];
    const float* v_w    = (const float*)d_in[19];
    const float* v_b    = (const float*)d_in[20];
    const float* fcv_w  = (const float*)d_in[21];
    const float* fcv_b  = (const float*)d_in[22];
    const float* proj_w = (const float*)d_in[23];
    const float* proj_b = (const float*)d_in[24];
    const float* w1     = (const float*)d_in[25];
    const float* b1     = (const float*)d_in[26];
    const float* w2     = (const float*)d_in[27];
    const float* b2     = (const float*)d_in[28];
    float* out = (float*)d_out;

    char* p = (char*)d_ws;
    auto alloc = [&](size_t bytes) { char* q = p; p += (bytes + 255) & ~(size_t)255; return q; };
    u16*   x1cl   = (u16*)alloc(37748736);   // [B][M][256] bf16
    u16*   nqb    = (u16*)alloc(9437184);    // [BT][N][64] / [B][M][64]
    u16*   nkb    = (u16*)alloc(9437184);
    u16*   SE     = (u16*)alloc(113246208);  // [BT][N][N] bf16 exp-scores
    u16*   AT2    = (u16*)alloc(113246208);  // [BT][w][v] bf16
    u16*   v1n    = (u16*)alloc(9437184);    // [BT][64][N]
    float* atT    = (float*)alloc(3538944);  // [B][N][12][12]
    u16*   hb     = (u16*)alloc(18874368);   // [B][M][128]
    u16*   vg     = (u16*)alloc(18874368);   // [B][M][128]
    float* rowsum = (float*)alloc(294912);   // [BT][N]
    u16*   WB     = (u16*)alloc(1081344);    // bf16 weights
    // Aliases (lifetime-checked): SE dead after attn_fin; AT2 dead after node_agg.
    float* xr   = (float*)SE;                            // [B][256][M] fp32
    u16*   x2cl = AT2;                                   // [B][M][256] bf16
    u16*   g1   = (u16*)((char*)AT2 + 37748736);         // [B][M][512] bf16

    dim3 blk(256);
    zero_f<<<dim3(288), blk, 0, stream>>>(rowsum);
    cvt_w<<<dim3(2112), blk, 0, stream>>>(Wnq, Wnk, Wtq, Wtk, v_w, fcv_w, proj_w,
                                          w1, w2, WB);
    ln_cl<<<dim3(144, nB), blk, 0, stream>>>(x, ln1w, ln1b, x1cl);
    gemm_proj<64, 0><<<dim3(144, 1, nB), blk, 0, stream>>>(x1cl, WB + 0, bnq, nqb);
    gemm_proj<64, 0><<<dim3(144, 1, nB), blk, 0, stream>>>(x1cl, WB + 16384, bnk, nkb);
    scores_k<<<dim3(12, 12, nB * nT), blk, 0, stream>>>(nqb, nkb, Bn, SE, rowsum);
    attn_fin<<<dim3(12, 12, nB * nT), blk, 0, stream>>>(SE, adj, rowsum, AT2);
    gemm_proj<64, 1><<<dim3(144, 1, nB), blk, 0, stream>>>(x1cl, WB + 32768, btq, nqb);
    gemm_proj<64, 1><<<dim3(144, 1, nB), blk, 0, stream>>>(x1cl, WB + 49152, btk, nkb);
    time_attn<<<dim3(nB * nN), dim3(192), 0, stream>>>(nqb, nkb, Bt, atT);
    gemm_proj<64, 2><<<dim3(144, 1, nB), blk, 0, stream>>>(x1cl, WB + 65536, v_b, v1n);
    node_agg_k<<<dim3(12, 1, nB * nT), blk, 0, stream>>>(v1n, AT2, hb);
    time_agg_k<<<dim3(12, nB), blk, 0, stream>>>(v1n, atT, hb);
    gemm_proj<128, 1><<<dim3(144, 2, nB), blk, 0, stream>>>(x1cl, WB + 81920, fcv_b, vg);
    prodproj_k<<<dim3(144, 4, nB), blk, 0, stream>>>(hb, vg, WB + 114688, proj_b, x, xr);
    ln_cl<<<dim3(144, nB), blk, 0, stream>>>(xr, ln2w, ln2b, x2cl);
    ffn1_k<<<dim3(144, 8, nB), blk, 0, stream>>>(x2cl, WB + 147456, b1, g1);
    ffn2_k<<<dim3(144, 4, nB), blk, 0, stream>>>(g1, WB + 409600, b2, xr, out);
}